// Round 3
// baseline (2718.476 us; speedup 1.0000x reference)
//
#include <hip/hip_runtime.h>
#include <stdint.h>

#define NCLS 80
#define MAXB 150
#define BATCH 16
#define NANCH 25200
#define CAP 4096
#define CAP2 12000   // hard bound: 80 classes * 150 kept max

typedef unsigned long long u64;
typedef unsigned int u32;

__device__ __forceinline__ float sigm(float x) { return 1.0f / (1.0f + expf(-x)); }

// ---------------- Pass 1: fused decode (all 3 levels) + wave-aggregated append ----
// Grid: (99, BATCH). chunks/image: L0(g=20):5, L1(g=40):19, L2(g=80):75.
// Block = 256 threads, one image => all lanes of a wave share b (and c in the
// class loop) => one atomicAdd per wave per hit-class via ballot aggregation.
__global__ __launch_bounds__(256) void decode_kernel(
    const float* __restrict__ p0, const float* __restrict__ p1,
    const float* __restrict__ p2, float* __restrict__ boxes_ws,
    u64* __restrict__ cand_keys, int* __restrict__ cand_cnt) {
  int cx = blockIdx.x, b = blockIdx.y, tid = threadIdx.x;
  int lvl, lc;
  if (cx < 5) { lvl = 0; lc = cx; }
  else if (cx < 24) { lvl = 1; lc = cx - 5; }
  else { lvl = 2; lc = cx - 24; }
  const int gtab[3] = {20, 40, 80};
  const float rtab[3] = {32.f, 16.f, 8.f};
  const int nbt[3] = {0, 1200, 6000};
  const int nrt[3] = {1200, 4800, 19200};
  const float awt[3][3] = {{116.f, 156.f, 373.f}, {30.f, 62.f, 59.f}, {10.f, 16.f, 33.f}};
  const float aht[3][3] = {{90.f, 198.f, 326.f}, {61.f, 45.f, 119.f}, {13.f, 30.f, 23.f}};
  const float* fm = (lvl == 0) ? p0 : ((lvl == 1) ? p1 : p2);
  int g = gtab[lvl], nrec = nrt[lvl];
  float ratio = rtab[lvl];
  int r = lc * 256 + tid;
  if (r >= nrec) return;
  int cell = r / 3, a = r - cell * 3;
  int y = cell / g, x = cell - y * g;
  const float* p = fm + ((size_t)(b * g * g + cell) * 255 + a * 85);
  float cx_ = (sigm(p[0]) + (float)x) * ratio;
  float cy_ = (sigm(p[1]) + (float)y) * ratio;
  float w = expf(p[2]) * awt[lvl][a];
  float hh = expf(p[3]) * aht[lvl][a];
  float cs = sigm(p[4]);
  int n = nbt[lvl] + r;
  reinterpret_cast<float4*>(boxes_ws)[(size_t)b * NANCH + n] =
      make_float4(cx_ - w * 0.5f, cy_ - hh * 0.5f, cx_ + w * 0.5f, cy_ + hh * 0.5f);
  // score = cs*ps <= cs in fp32 -> cs > 0.9 is an exact-safe necessary condition
  if (cs > 0.9f) {
    int lane = tid & 63;
    u64 ltmask = (1ull << lane) - 1;
    for (int c = 0; c < NCLS; ++c) {
      float pl = p[5 + c];
      float s = 0.f;
      if (pl > 2.19f) s = cs * sigm(pl);  // sigm(2.19)<0.9 -> lossless pre-cull
      bool hit = s > 0.9f;
      u64 mask = __ballot(hit);  // all active lanes share bc
      if (mask) {
        int bc = b * NCLS + c;
        int leader = __ffsll(mask) - 1;
        int base = 0;
        if (lane == leader) base = atomicAdd(&cand_cnt[bc], __popcll(mask));
        base = __shfl(base, leader);
        if (hit) {
          int pos = base + (int)__popcll(mask & ltmask);
          if (pos < CAP)  // high = score bits, low = ~anchor (desc sort => idx asc ties)
            cand_keys[(size_t)bc * CAP + pos] =
                ((u64)__float_as_uint(s) << 32) | (u32)(0xFFFFFFFFu - (u32)n);
        }
      }
    }
  }
}

// ---------------- Pass 2: rank-select top-150 + single-wave greedy NMS ----------
__global__ __launch_bounds__(256) void nms_kernel(
    const u64* __restrict__ cand_keys, const int* __restrict__ cand_cnt,
    const float* __restrict__ boxes_ws,
    u64* __restrict__ img_keys, int* __restrict__ img_cnt) {
  __shared__ u64 sk[CAP];       // 32 KB
  __shared__ u64 slot[MAXB];    // top-150 keys by exact rank
  __shared__ float4 sbox[MAXB];
  __shared__ float sarea[MAXB];
  int bc = blockIdx.x;
  int b = bc / NCLS, c = bc - b * NCLS;
  int tid = threadIdx.x;
  int count = cand_cnt[bc];
  if (count > CAP) count = CAP;
  const u64* src = cand_keys + (size_t)bc * CAP;
  for (int i = tid; i < count; i += 256) sk[i] = src[i];
  if (tid < MAXB) slot[tid] = 0;
  __syncthreads();
  // exact rank selection (keys unique): rank = #{j: key_j > key_i}
  for (int i = tid; i < count; i += 256) {
    u64 k = sk[i];
    int rank = 0;
    for (int j = 0; j < count; ++j) rank += (sk[j] > k) ? 1 : 0;
    if (rank < MAXB) slot[rank] = k;
  }
  __syncthreads();
  if (tid < MAXB) {
    u64 k = slot[tid];
    float4 bx = make_float4(0.f, 0.f, 0.f, 0.f);
    if (k) {
      int n = (int)(0xFFFFFFFFu - (u32)(k & 0xFFFFFFFFu));
      bx = reinterpret_cast<const float4*>(boxes_ws)[(size_t)b * NANCH + n];
    }
    sbox[tid] = bx;
    sarea[tid] = (bx.z - bx.x) * (bx.w - bx.y);
  }
  __syncthreads();
  // single-wave greedy NMS: lane owns j in {lane, lane+64, lane+128}; no barriers.
  if (tid < 64) {
    u32 validm = 0, supm = 0;
    float4 myb[3];
    float mya[3];
    for (int s = 0; s < 3; ++s) {
      int j = tid + 64 * s;
      myb[s] = make_float4(0.f, 0.f, 0.f, 0.f);
      mya[s] = 0.f;
      if (j < MAXB && slot[j] != 0) {
        validm |= 1u << s;
        myb[s] = sbox[j];
        mya[s] = sarea[j];
      }
    }
    for (int i = 0; i < MAXB - 1; ++i) {
      int owner = i & 63, si = i >> 6;
      u32 f = __shfl(validm & ~supm, owner);  // uniform: keep_i from owner lane
      if ((f >> si) & 1) {
        float4 bi = sbox[i];
        float ai = sarea[i];
        for (int s = 0; s < 3; ++s) {
          int j = tid + 64 * s;
          if (j > i && j < MAXB && ((validm >> s) & 1) && !((supm >> s) & 1)) {
            float ltx = fmaxf(bi.x, myb[s].x);
            float lty = fmaxf(bi.y, myb[s].y);
            float rbx = fminf(bi.z, myb[s].z);
            float rby = fminf(bi.w, myb[s].w);
            float iw = fmaxf(rbx - ltx, 0.f);
            float ih = fmaxf(rby - lty, 0.f);
            float inter = iw * ih;
            float iou = inter / (ai + mya[s] - inter + 1e-9f);  // ref op order
            if (iou > 0.1f) supm |= 1u << s;
          }
        }
      }
    }
    // wave-aggregated append of kept entries to per-image list
    u32 keepm = validm & ~supm;
    u64 m0 = __ballot(keepm & 1u);
    u64 m1 = __ballot((keepm >> 1) & 1u);
    u64 m2 = __ballot((keepm >> 2) & 1u);
    int total = (int)(__popcll(m0) + __popcll(m1) + __popcll(m2));
    if (total > 0) {
      int base = 0;
      if (tid == 0) base = atomicAdd(&img_cnt[b], total);
      base = __shfl(base, 0);
      u64 lt = (1ull << tid) - 1;
      int off0 = (int)__popcll(m0 & lt);
      int off1 = (int)(__popcll(m0) + __popcll(m1 & lt));
      int off2 = (int)(__popcll(m0) + __popcll(m1) + __popcll(m2 & lt));
      for (int s = 0; s < 3; ++s) {
        if ((keepm >> s) & 1) {
          int j = tid + 64 * s;  // j == rank == top_k position
          u64 k = slot[j];
          u32 e = (u32)(c * MAXB + j);
          u32 anchor = (u32)(0xFFFFFFFFu - (u32)(k & 0xFFFFFFFFu));
          int pos = base + ((s == 0) ? off0 : ((s == 1) ? off1 : off2));
          // key = [score:32][(0x3FFF - e):14][anchor:15]
          img_keys[(size_t)b * CAP2 + pos] =
              ((k >> 32) << 32) | ((u64)(0x3FFFu - e) << 15) | anchor;
        }
      }
    }
  }
}

// ---------------- Pass 3: per-image top-150 by rank selection ----------------
__global__ __launch_bounds__(1024) void final_kernel(
    const u64* __restrict__ img_keys, const int* __restrict__ img_cnt,
    const float* __restrict__ boxes_ws, float* __restrict__ out) {
  __shared__ u64 keys[CAP2];  // 96 KB
  __shared__ u64 slot[MAXB];
  int b = blockIdx.x, tid = threadIdx.x;
  int L = img_cnt[b];
  if (L > CAP2) L = CAP2;
  for (int i = tid; i < L; i += 1024) keys[i] = img_keys[(size_t)b * CAP2 + i];
  if (tid < MAXB) slot[tid] = 0;
  __syncthreads();
  for (int i = tid; i < L; i += 1024) {
    u64 k = keys[i];
    int rank = 0;
    for (int j = 0; j < L; ++j) rank += (keys[j] > k) ? 1 : 0;
    if (rank < MAXB) slot[rank] = k;
  }
  __syncthreads();
  if (tid < MAXB) {
    u64 k = slot[tid];
    float* ob = out;                      // [B][150][4]
    float* osc = out + BATCH * MAXB * 4;  // [B][150]
    float* olb = out + BATCH * MAXB * 5;  // [B][150] labels (as float)
    float* q = ob + ((size_t)b * MAXB + tid) * 4;
    if (k) {
      u32 e = 0x3FFFu - (u32)((k >> 15) & 0x3FFFu);
      int c = (int)(e / MAXB);
      int anchor = (int)(k & 0x7FFFu);
      float4 bx = reinterpret_cast<const float4*>(boxes_ws)[(size_t)b * NANCH + anchor];
      q[0] = bx.x; q[1] = bx.y; q[2] = bx.z; q[3] = bx.w;
      osc[(size_t)b * MAXB + tid] = __uint_as_float((u32)(k >> 32));
      olb[(size_t)b * MAXB + tid] = (float)c;
    } else {
      q[0] = q[1] = q[2] = q[3] = -1.f;
      osc[(size_t)b * MAXB + tid] = -1.f;
      olb[(size_t)b * MAXB + tid] = -1.f;
    }
  }
}

extern "C" void kernel_launch(void* const* d_in, const int* in_sizes, int n_in,
                              void* d_out, int out_size, void* d_ws, size_t ws_size,
                              hipStream_t stream) {
  (void)in_sizes; (void)n_in; (void)out_size; (void)ws_size;
  const float* p0 = (const float*)d_in[0];  // [16,20,20,255] anchors[6:9]
  const float* p1 = (const float*)d_in[1];  // [16,40,40,255] anchors[3:6]
  const float* p2 = (const float*)d_in[2];  // [16,80,80,255] anchors[0:3]
  char* ws = (char*)d_ws;
  float* boxes_ws = (float*)ws;              // 16*25200*16 B          -> 6,451,200
  int* cand_cnt = (int*)(ws + 6451200);      // 1280 i32               -> 6,456,320
  int* img_cnt = (int*)(ws + 6456320);       // 16 i32                 -> 6,456,384
  u64* cand_keys = (u64*)(ws + 6456384);     // 1280*4096 u64          -> 48,399,424
  u64* img_keys = (u64*)(ws + 48399424);     // 16*12000 u64           -> 49,935,424

  hipMemsetAsync(cand_cnt, 0, (NCLS * BATCH + BATCH) * sizeof(int), stream);

  decode_kernel<<<dim3(99, BATCH), 256, 0, stream>>>(p0, p1, p2, boxes_ws,
                                                     cand_keys, cand_cnt);
  nms_kernel<<<BATCH * NCLS, 256, 0, stream>>>(cand_keys, cand_cnt, boxes_ws,
                                               img_keys, img_cnt);
  final_kernel<<<BATCH, 1024, 0, stream>>>(img_keys, img_cnt, boxes_ws, (float*)d_out);
}

// Round 4
// 653.302 us; speedup vs baseline: 4.1611x; 4.1611x over previous
//
#include <hip/hip_runtime.h>
#include <stdint.h>

#define NCLS 80
#define MAXB 150
#define BATCH 16
#define NANCH 25200
#define CAP 4096
#define CAP2 12000   // hard bound: 80 classes * 150 kept max

typedef unsigned long long u64;
typedef unsigned int u32;
typedef float f4 __attribute__((ext_vector_type(4)));
typedef f4 f4u __attribute__((aligned(4)));  // 4B-aligned vector load

__device__ __forceinline__ float sigm(float x) { return 1.0f / (1.0f + expf(-x)); }

// ---------------- Pass 1: fused decode, 4 records/thread, batched loads ----------
// Grid: (26, BATCH): chunks of 1024 records -> L0(g=20):2, L1(g=40):5, L2(g=80):19.
// One image per block => wave-uniform b,c => ballot-aggregated appends.
__global__ __launch_bounds__(256) void decode_kernel(
    const float* __restrict__ p0, const float* __restrict__ p1,
    const float* __restrict__ p2, float* __restrict__ boxes_ws,
    u64* __restrict__ cand_keys, int* __restrict__ cand_cnt) {
  int cxb = blockIdx.x, b = blockIdx.y, tid = threadIdx.x;
  int lvl, lc;
  if (cxb < 2) { lvl = 0; lc = cxb; }
  else if (cxb < 7) { lvl = 1; lc = cxb - 2; }
  else { lvl = 2; lc = cxb - 7; }
  const int gtab[3] = {20, 40, 80};
  const float rtab[3] = {32.f, 16.f, 8.f};
  const int nbt[3] = {0, 1200, 6000};
  const float awt[3][3] = {{116.f, 156.f, 373.f}, {30.f, 62.f, 59.f}, {10.f, 16.f, 33.f}};
  const float aht[3][3] = {{90.f, 198.f, 326.f}, {61.f, 45.f, 119.f}, {13.f, 30.f, 23.f}};
  const float* fm = (lvl == 0) ? p0 : ((lvl == 1) ? p1 : p2);
  int g = gtab[lvl];
  int nrec = g * g * 3;
  float ratio = rtab[lvl];
  int lane = tid & 63;
  u64 ltm = (1ull << lane) - 1;

  int r[4];
  bool val[4];
  const float* pp[4];
  f4 h[4];
  float cf[4];
#pragma unroll
  for (int s = 0; s < 4; ++s) {
    int rr = lc * 1024 + s * 256 + tid;
    r[s] = rr;
    val[s] = rr < nrec;
    const float* p = fm + ((size_t)b * nrec + (val[s] ? rr : 0)) * 85;
    pp[s] = p;
    if (val[s]) { h[s] = *(const f4u*)p; cf[s] = p[4]; }
    else { cf[s] = -100.f; }
  }
  float cs[4];
#pragma unroll
  for (int s = 0; s < 4; ++s) {
    cs[s] = 0.f;
    if (val[s]) {
      int rr = r[s];
      int cell = rr / 3, a = rr - 3 * cell;
      int yy = cell / g, xx = cell - yy * g;
      float cx_ = (sigm(h[s].x) + (float)xx) * ratio;
      float cy_ = (sigm(h[s].y) + (float)yy) * ratio;
      float w = expf(h[s].z) * awt[lvl][a];
      float hh = expf(h[s].w) * aht[lvl][a];
      int n = nbt[lvl] + rr;
      reinterpret_cast<float4*>(boxes_ws)[(size_t)b * NANCH + n] = make_float4(
          cx_ - w * 0.5f, cy_ - hh * 0.5f, cx_ + w * 0.5f, cy_ + hh * 0.5f);
      cs[s] = sigm(cf[s]);  // score<=cs in fp32 -> cs>0.9 is a lossless gate
    }
  }
  for (int s = 0; s < 4; ++s) {
    bool act = val[s] && cs[s] > 0.9f;
    u64 anym = __ballot(act);   // uniform across wave
    if (!anym) continue;        // whole wave skips together
    f4 pr[20];
    if (act) {
#pragma unroll
      for (int k = 0; k < 20; ++k) pr[k] = *(const f4u*)(pp[s] + 5 + 4 * k);
    }
    float csv = cs[s];
    u32 nkey = 0xFFFFFFFFu - (u32)(nbt[lvl] + r[s]);
#pragma unroll
    for (int c = 0; c < NCLS; ++c) {
      float pl = act ? pr[c >> 2][c & 3] : -100.f;
      bool hit = false;
      float sc = 0.f;
      if (pl > 2.19f) {  // sigm(2.19)=0.8993<0.9 -> lossless pre-cull
        sc = csv * sigm(pl);
        hit = sc > 0.9f;
      }
      u64 mask = __ballot(hit);
      if (mask) {
        int bc = b * NCLS + c;
        int leader = __ffsll(mask) - 1;
        int base = 0;
        if (lane == leader) base = atomicAdd(&cand_cnt[bc], __popcll(mask));
        base = __shfl(base, leader);
        if (hit) {
          int pos = base + (int)__popcll(mask & ltm);
          if (pos < CAP)  // high = score bits, low = ~anchor (desc => idx-asc ties)
            cand_keys[(size_t)bc * CAP + pos] = ((u64)__float_as_uint(sc) << 32) | nkey;
        }
      }
    }
  }
}

// ---------------- Pass 2: rank-select top-150 + single-wave greedy NMS ----------
__global__ __launch_bounds__(256) void nms_kernel(
    const u64* __restrict__ cand_keys, const int* __restrict__ cand_cnt,
    const float* __restrict__ boxes_ws,
    u64* __restrict__ img_keys, int* __restrict__ img_cnt) {
  __shared__ u64 sk[CAP];       // 32 KB
  __shared__ u64 slot[MAXB];    // top-150 keys by exact rank
  __shared__ float4 sbox[MAXB];
  __shared__ float sarea[MAXB];
  int bc = blockIdx.x;
  int b = bc / NCLS, c = bc - b * NCLS;
  int tid = threadIdx.x;
  int count = cand_cnt[bc];
  if (count > CAP) count = CAP;
  const u64* src = cand_keys + (size_t)bc * CAP;
  for (int i = tid; i < count; i += 256) sk[i] = src[i];
  if (tid < MAXB) slot[tid] = 0;
  __syncthreads();
  // exact rank selection (keys unique): rank = #{j: key_j > key_i}
  for (int i = tid; i < count; i += 256) {
    u64 k = sk[i];
    int rank = 0;
    for (int j = 0; j < count; ++j) rank += (sk[j] > k) ? 1 : 0;
    if (rank < MAXB) slot[rank] = k;
  }
  __syncthreads();
  if (tid < MAXB) {
    u64 k = slot[tid];
    float4 bx = make_float4(0.f, 0.f, 0.f, 0.f);
    if (k) {
      int n = (int)(0xFFFFFFFFu - (u32)(k & 0xFFFFFFFFu));
      bx = reinterpret_cast<const float4*>(boxes_ws)[(size_t)b * NANCH + n];
    }
    sbox[tid] = bx;
    sarea[tid] = (bx.z - bx.x) * (bx.w - bx.y);
  }
  __syncthreads();
  // single-wave greedy NMS: lane owns j in {lane, lane+64, lane+128}; no barriers.
  if (tid < 64) {
    u32 validm = 0, supm = 0;
    float4 myb[3];
    float mya[3];
    for (int s = 0; s < 3; ++s) {
      int j = tid + 64 * s;
      myb[s] = make_float4(0.f, 0.f, 0.f, 0.f);
      mya[s] = 0.f;
      if (j < MAXB && slot[j] != 0) {
        validm |= 1u << s;
        myb[s] = sbox[j];
        mya[s] = sarea[j];
      }
    }
    for (int i = 0; i < MAXB - 1; ++i) {
      int owner = i & 63, si = i >> 6;
      u32 f = __shfl(validm & ~supm, owner);  // keep_i broadcast from owner lane
      if ((f >> si) & 1) {
        float4 bi = sbox[i];
        float ai = sarea[i];
        for (int s = 0; s < 3; ++s) {
          int j = tid + 64 * s;
          if (j > i && j < MAXB && ((validm >> s) & 1) && !((supm >> s) & 1)) {
            float ltx = fmaxf(bi.x, myb[s].x);
            float lty = fmaxf(bi.y, myb[s].y);
            float rbx = fminf(bi.z, myb[s].z);
            float rby = fminf(bi.w, myb[s].w);
            float iw = fmaxf(rbx - ltx, 0.f);
            float ih = fmaxf(rby - lty, 0.f);
            float inter = iw * ih;
            float iou = inter / (ai + mya[s] - inter + 1e-9f);  // ref op order
            if (iou > 0.1f) supm |= 1u << s;
          }
        }
      }
    }
    // wave-aggregated append of kept entries to per-image list
    u32 keepm = validm & ~supm;
    u64 m0 = __ballot(keepm & 1u);
    u64 m1 = __ballot((keepm >> 1) & 1u);
    u64 m2 = __ballot((keepm >> 2) & 1u);
    int total = (int)(__popcll(m0) + __popcll(m1) + __popcll(m2));
    if (total > 0) {
      int base = 0;
      if (tid == 0) base = atomicAdd(&img_cnt[b], total);
      base = __shfl(base, 0);
      u64 lt = (1ull << tid) - 1;
      int off0 = (int)__popcll(m0 & lt);
      int off1 = (int)(__popcll(m0) + __popcll(m1 & lt));
      int off2 = (int)(__popcll(m0) + __popcll(m1) + __popcll(m2 & lt));
      for (int s = 0; s < 3; ++s) {
        if ((keepm >> s) & 1) {
          int j = tid + 64 * s;  // j == rank == top_k position
          u64 k = slot[j];
          u32 e = (u32)(c * MAXB + j);
          u32 anchor = (u32)(0xFFFFFFFFu - (u32)(k & 0xFFFFFFFFu));
          int pos = base + ((s == 0) ? off0 : ((s == 1) ? off1 : off2));
          // key = [score:32][(0x3FFF - e):14][anchor:15]  (unique per entry)
          img_keys[(size_t)b * CAP2 + pos] =
              ((k >> 32) << 32) | ((u64)(0x3FFFu - e) << 15) | anchor;
        }
      }
    }
  }
}

// ---------------- Pass 3: per-image top-150 via 150-round argmax ----------------
__global__ __launch_bounds__(1024) void final_kernel(
    const u64* __restrict__ img_keys, const int* __restrict__ img_cnt,
    const float* __restrict__ boxes_ws, float* __restrict__ out) {
  __shared__ u64 keys[CAP2];  // 96 KB
  __shared__ u64 wmax[16];
  __shared__ u64 swin;
  int b = blockIdx.x, tid = threadIdx.x;
  int L = img_cnt[b];
  if (L > CAP2) L = CAP2;
  for (int i = tid; i < L; i += 1024) keys[i] = img_keys[(size_t)b * CAP2 + i];
  __syncthreads();
  float* ob = out;                      // [B][150][4]
  float* osc = out + BATCH * MAXB * 4;  // [B][150]
  float* olb = out + BATCH * MAXB * 5;  // [B][150] labels (as float)
  for (int r = 0; r < MAXB; ++r) {
    u64 lm = 0;
    int lpos = -1;
    for (int i = tid; i < L; i += 1024) {
      u64 kk = keys[i];
      if (kk > lm) { lm = kk; lpos = i; }
    }
    u64 m = lm;
    for (int off = 32; off > 0; off >>= 1) {
      u64 o = __shfl_xor(m, off);
      if (o > m) m = o;
    }
    if ((tid & 63) == 0) wmax[tid >> 6] = m;
    __syncthreads();
    if (tid < 64) {
      u64 m2 = (tid < 16) ? wmax[tid] : 0;
      for (int off = 8; off > 0; off >>= 1) {
        u64 o = __shfl_xor(m2, off);
        if (o > m2) m2 = o;
      }
      if (tid == 0) swin = m2;
    }
    __syncthreads();
    u64 w = swin;
    if (w == 0) {  // exhausted -> -1 row
      if (tid == 0) {
        float* q = ob + ((size_t)b * MAXB + r) * 4;
        q[0] = q[1] = q[2] = q[3] = -1.f;
        osc[(size_t)b * MAXB + r] = -1.f;
        olb[(size_t)b * MAXB + r] = -1.f;
      }
    } else if (lm == w && lpos >= 0) {  // unique owner (keys unique)
      keys[lpos] = 0;
      u32 e = 0x3FFFu - (u32)((w >> 15) & 0x3FFFu);
      int c = (int)(e / MAXB);
      int anchor = (int)(w & 0x7FFFu);
      float4 bx = reinterpret_cast<const float4*>(boxes_ws)[(size_t)b * NANCH + anchor];
      float* q = ob + ((size_t)b * MAXB + r) * 4;
      q[0] = bx.x; q[1] = bx.y; q[2] = bx.z; q[3] = bx.w;
      osc[(size_t)b * MAXB + r] = __uint_as_float((u32)(w >> 32));
      olb[(size_t)b * MAXB + r] = (float)c;
    }
    __syncthreads();  // winner-clear visible before next round
  }
}

extern "C" void kernel_launch(void* const* d_in, const int* in_sizes, int n_in,
                              void* d_out, int out_size, void* d_ws, size_t ws_size,
                              hipStream_t stream) {
  (void)in_sizes; (void)n_in; (void)out_size; (void)ws_size;
  const float* p0 = (const float*)d_in[0];  // [16,20,20,255] anchors[6:9]
  const float* p1 = (const float*)d_in[1];  // [16,40,40,255] anchors[3:6]
  const float* p2 = (const float*)d_in[2];  // [16,80,80,255] anchors[0:3]
  char* ws = (char*)d_ws;
  float* boxes_ws = (float*)ws;              // 16*25200*16 B          -> 6,451,200
  int* cand_cnt = (int*)(ws + 6451200);      // 1280 i32               -> 6,456,320
  int* img_cnt = (int*)(ws + 6456320);       // 16 i32                 -> 6,456,384
  u64* cand_keys = (u64*)(ws + 6456384);     // 1280*4096 u64          -> 48,399,424
  u64* img_keys = (u64*)(ws + 48399424);     // 16*12000 u64           -> 49,935,424

  hipMemsetAsync(cand_cnt, 0, (NCLS * BATCH + BATCH) * sizeof(int), stream);

  decode_kernel<<<dim3(26, BATCH), 256, 0, stream>>>(p0, p1, p2, boxes_ws,
                                                     cand_keys, cand_cnt);
  nms_kernel<<<BATCH * NCLS, 256, 0, stream>>>(cand_keys, cand_cnt, boxes_ws,
                                               img_keys, img_cnt);
  final_kernel<<<BATCH, 1024, 0, stream>>>(img_keys, img_cnt, boxes_ws, (float*)d_out);
}

// Round 5
// 528.319 us; speedup vs baseline: 5.1455x; 1.2366x over previous
//
#include <hip/hip_runtime.h>
#include <stdint.h>

#define NCLS 80
#define MAXB 150
#define BATCH 16
#define NANCH 25200
#define CAP 4096
#define CAP2 12000   // hard bound: 80 classes * 150 kept max
#define NBINS 411    // score hi-bits (0x3F666666,0x3F800000] -> bins 0..410
#define SELCAP 2048

typedef unsigned long long u64;
typedef unsigned int u32;

__device__ __forceinline__ float sigm(float x) { return 1.0f / (1.0f + expf(-x)); }

// ---------------- Pass 1: one wave per record, fully-coalesced decode ------------
// 1024 thr/block = 16 waves = 16 records. Wave reads its whole 85-float record
// contiguously (lane l: p[5+l]; l<16: p[69+l]; l<5: header). Record index is
// wave-uniform -> cs-gate and anchor selects are uniform; hit lanes touch
// DISTINCT class counters -> no intra-wave atomic serialization.
__global__ __launch_bounds__(1024) void decode_kernel(
    const float* __restrict__ p0, const float* __restrict__ p1,
    const float* __restrict__ p2, float* __restrict__ boxes_ws,
    u64* __restrict__ cand_keys, int* __restrict__ cand_cnt) {
  int W = blockIdx.x * 16 + (threadIdx.x >> 6);  // global record id, level-major
  int lane = threadIdx.x & 63;
  int lvl, b, r;
  if (W < 19200) { lvl = 0; b = W / 1200; r = W - b * 1200; }
  else if (W < 96000) { int V = W - 19200; lvl = 1; b = V / 4800; r = V - b * 4800; }
  else { int V = W - 96000; lvl = 2; b = V / 19200; r = V - b * 19200; }
  const int gtab[3] = {20, 40, 80};
  const float rtab[3] = {32.f, 16.f, 8.f};
  const int nbt[3] = {0, 1200, 6000};
  const float awt[3][3] = {{116.f, 156.f, 373.f}, {30.f, 62.f, 59.f}, {10.f, 16.f, 33.f}};
  const float aht[3][3] = {{90.f, 198.f, 326.f}, {61.f, 45.f, 119.f}, {13.f, 30.f, 23.f}};
  const float* fm = (lvl == 0) ? p0 : ((lvl == 1) ? p1 : p2);
  int g = gtab[lvl];
  const float* p = fm + ((size_t)b * (g * g * 3) + r) * 85;
  // coalesced loads: entire record in 3 wave-level requests
  float q0 = p[5 + lane];                          // classes 0..63
  float q1 = (lane < 16) ? p[69 + lane] : 0.f;     // classes 64..79
  float hv = (lane < 5) ? p[lane] : 0.f;           // header tx,ty,tw,th,conf
  float tx = __shfl(hv, 0), ty = __shfl(hv, 1), tw = __shfl(hv, 2),
        th = __shfl(hv, 3), tc = __shfl(hv, 4);
  int cell = r / 3, a = r - 3 * cell;
  int yy = cell / g, xx = cell - yy * g;
  float ratio = rtab[lvl];
  float cx = (sigm(tx) + (float)xx) * ratio;
  float cy = (sigm(ty) + (float)yy) * ratio;
  float w = expf(tw) * awt[lvl][a];
  float hh = expf(th) * aht[lvl][a];
  int n = nbt[lvl] + r;
  if (lane == 0)
    reinterpret_cast<float4*>(boxes_ws)[(size_t)b * NANCH + n] = make_float4(
        cx - w * 0.5f, cy - hh * 0.5f, cx + w * 0.5f, cy + hh * 0.5f);
  float cs = sigm(tc);  // score<=cs in fp32 -> cs>0.9 is a lossless gate (uniform)
  if (cs > 0.9f) {
    u32 nkey = 0xFFFFFFFFu - (u32)n;
    if (q0 > 2.19f) {  // sigm(2.19)=0.8993<0.9 -> lossless pre-cull
      float s = cs * sigm(q0);
      if (s > 0.9f) {
        int bc = b * NCLS + lane;
        int pos = atomicAdd(&cand_cnt[bc], 1);
        if (pos < CAP)
          cand_keys[(size_t)bc * CAP + pos] = ((u64)__float_as_uint(s) << 32) | nkey;
      }
    }
    if (lane < 16 && q1 > 2.19f) {
      float s = cs * sigm(q1);
      if (s > 0.9f) {
        int bc = b * NCLS + 64 + lane;
        int pos = atomicAdd(&cand_cnt[bc], 1);
        if (pos < CAP)
          cand_keys[(size_t)bc * CAP + pos] = ((u64)__float_as_uint(s) << 32) | nkey;
      }
    }
  }
}

// ---------------- Pass 2: rank-select top-150 + single-wave greedy NMS ----------
__global__ __launch_bounds__(256) void nms_kernel(
    const u64* __restrict__ cand_keys, const int* __restrict__ cand_cnt,
    const float* __restrict__ boxes_ws,
    u64* __restrict__ img_keys, int* __restrict__ img_cnt) {
  __shared__ u64 sk[CAP];       // 32 KB
  __shared__ u64 slot[MAXB];    // top-150 keys by exact rank
  __shared__ float4 sbox[MAXB];
  __shared__ float sarea[MAXB];
  int bc = blockIdx.x;
  int b = bc / NCLS, c = bc - b * NCLS;
  int tid = threadIdx.x;
  int count = cand_cnt[bc];
  if (count > CAP) count = CAP;
  const u64* src = cand_keys + (size_t)bc * CAP;
  for (int i = tid; i < count; i += 256) sk[i] = src[i];
  if (tid < MAXB) slot[tid] = 0;
  __syncthreads();
  // exact rank selection (keys unique); inner sk[j] is uniform -> LDS broadcast
  for (int i = tid; i < count; i += 256) {
    u64 k = sk[i];
    int rank = 0;
    for (int j = 0; j < count; ++j) rank += (sk[j] > k) ? 1 : 0;
    if (rank < MAXB) slot[rank] = k;
  }
  __syncthreads();
  if (tid < MAXB) {
    u64 k = slot[tid];
    float4 bx = make_float4(0.f, 0.f, 0.f, 0.f);
    if (k) {
      int n = (int)(0xFFFFFFFFu - (u32)(k & 0xFFFFFFFFu));
      bx = reinterpret_cast<const float4*>(boxes_ws)[(size_t)b * NANCH + n];
    }
    sbox[tid] = bx;
    sarea[tid] = (bx.z - bx.x) * (bx.w - bx.y);
  }
  __syncthreads();
  // single-wave greedy NMS: lane owns j in {lane, lane+64, lane+128}; no barriers.
  if (tid < 64) {
    u32 validm = 0, supm = 0;
    float4 myb[3];
    float mya[3];
    for (int s = 0; s < 3; ++s) {
      int j = tid + 64 * s;
      myb[s] = make_float4(0.f, 0.f, 0.f, 0.f);
      mya[s] = 0.f;
      if (j < MAXB && slot[j] != 0) {
        validm |= 1u << s;
        myb[s] = sbox[j];
        mya[s] = sarea[j];
      }
    }
    for (int i = 0; i < MAXB - 1; ++i) {
      int owner = i & 63, si = i >> 6;
      u32 f = __shfl(validm & ~supm, owner);  // keep_i broadcast from owner lane
      if ((f >> si) & 1) {
        float4 bi = sbox[i];
        float ai = sarea[i];
        for (int s = 0; s < 3; ++s) {
          int j = tid + 64 * s;
          if (j > i && j < MAXB && ((validm >> s) & 1) && !((supm >> s) & 1)) {
            float ltx = fmaxf(bi.x, myb[s].x);
            float lty = fmaxf(bi.y, myb[s].y);
            float rbx = fminf(bi.z, myb[s].z);
            float rby = fminf(bi.w, myb[s].w);
            float iw = fmaxf(rbx - ltx, 0.f);
            float ih = fmaxf(rby - lty, 0.f);
            float inter = iw * ih;
            float iou = inter / (ai + mya[s] - inter + 1e-9f);  // ref op order
            if (iou > 0.1f) supm |= 1u << s;
          }
        }
      }
    }
    // wave-aggregated append of kept entries to per-image list
    u32 keepm = validm & ~supm;
    u64 m0 = __ballot(keepm & 1u);
    u64 m1 = __ballot((keepm >> 1) & 1u);
    u64 m2 = __ballot((keepm >> 2) & 1u);
    int total = (int)(__popcll(m0) + __popcll(m1) + __popcll(m2));
    if (total > 0) {
      int base = 0;
      if (tid == 0) base = atomicAdd(&img_cnt[b], total);
      base = __shfl(base, 0);
      u64 lt = (1ull << tid) - 1;
      int off0 = (int)__popcll(m0 & lt);
      int off1 = (int)(__popcll(m0) + __popcll(m1 & lt));
      int off2 = (int)(__popcll(m0) + __popcll(m1) + __popcll(m2 & lt));
      for (int s = 0; s < 3; ++s) {
        if ((keepm >> s) & 1) {
          int j = tid + 64 * s;  // j == rank == top_k position
          u64 k = slot[j];
          u32 e = (u32)(c * MAXB + j);
          u32 anchor = (u32)(0xFFFFFFFFu - (u32)(k & 0xFFFFFFFFu));
          int pos = base + ((s == 0) ? off0 : ((s == 1) ? off1 : off2));
          // key = [score:32][(0x3FFF - e):14][anchor:15]  (unique per entry)
          img_keys[(size_t)b * CAP2 + pos] =
              ((k >> 32) << 32) | ((u64)(0x3FFFu - e) << 15) | anchor;
        }
      }
    }
  }
}

// ---------------- Pass 3: per-image top-150 via exact histogram select ----------
// Scores in (0.9,1.0] -> hi bits in (0x3F666666, 0x3F800000]; bin = (hi-0x3F666000)>>12.
// Bins are bit-monotone: {bins >= T} is exactly the top-c_ge key set.
__global__ __launch_bounds__(1024) void final_kernel(
    const u64* __restrict__ img_keys, const int* __restrict__ img_cnt,
    const float* __restrict__ boxes_ws, float* __restrict__ out) {
  __shared__ u32 hist[NBINS];
  __shared__ u64 sel[SELCAP];   // 16 KB
  __shared__ u64 slot[MAXB];
  __shared__ int sT, sCge, nsel;
  int b = blockIdx.x, tid = threadIdx.x;
  int L = img_cnt[b];
  if (L > CAP2) L = CAP2;
  const u64* src = img_keys + (size_t)b * CAP2;
  for (int i = tid; i < NBINS; i += 1024) hist[i] = 0;
  if (tid < MAXB) slot[tid] = 0;
  if (tid == 0) nsel = 0;
  __syncthreads();
  for (int i = tid; i < L; i += 1024) {
    u32 hi = (u32)(src[i] >> 32);
    atomicAdd(&hist[(hi - 0x3F666000u) >> 12], 1u);
  }
  __syncthreads();
  if (tid == 0) {
    int target = (L < MAXB) ? L : MAXB;
    int acc = 0, T = 0;
    if (target > 0) {
      for (int j = NBINS - 1; j >= 0; --j) {
        acc += (int)hist[j];
        if (acc >= target) { T = j; break; }
      }
    }
    sT = T;
    sCge = acc;
  }
  __syncthreads();
  int T = sT, cge = sCge;
  float* ob = out;                      // [B][150][4]
  float* osc = out + BATCH * MAXB * 4;  // [B][150]
  float* olb = out + BATCH * MAXB * 5;  // [B][150] labels (as float)
  if (cge <= SELCAP) {
    // fast path: compact bins >= T, exact rank-select the small set
    for (int i = tid; i < L; i += 1024) {
      u64 k = src[i];
      if ((int)(((u32)(k >> 32) - 0x3F666000u) >> 12) >= T) {
        int pos = atomicAdd(&nsel, 1);
        sel[pos] = k;
      }
    }
    __syncthreads();
    int C = nsel;
    for (int i = tid; i < C; i += 1024) {
      u64 k = sel[i];
      int rank = 0;
      for (int j = 0; j < C; ++j) rank += (sel[j] > k) ? 1 : 0;  // LDS broadcast
      if (rank < MAXB) slot[rank] = k;
    }
    __syncthreads();
  } else {
    // fallback (pathological concentration): exact rank-select over global list
    for (int i = tid; i < L; i += 1024) {
      u64 k = src[i];
      int rank = 0;
      for (int j = 0; j < L; ++j) rank += (src[j] > k) ? 1 : 0;
      if (rank < MAXB) slot[rank] = k;
    }
    __syncthreads();
  }
  if (tid < MAXB) {
    u64 k = slot[tid];
    float* q = ob + ((size_t)b * MAXB + tid) * 4;
    if (k) {
      u32 e = 0x3FFFu - (u32)((k >> 15) & 0x3FFFu);
      int c = (int)(e / MAXB);
      int anchor = (int)(k & 0x7FFFu);
      float4 bx = reinterpret_cast<const float4*>(boxes_ws)[(size_t)b * NANCH + anchor];
      q[0] = bx.x; q[1] = bx.y; q[2] = bx.z; q[3] = bx.w;
      osc[(size_t)b * MAXB + tid] = __uint_as_float((u32)(k >> 32));
      olb[(size_t)b * MAXB + tid] = (float)c;
    } else {
      q[0] = q[1] = q[2] = q[3] = -1.f;
      osc[(size_t)b * MAXB + tid] = -1.f;
      olb[(size_t)b * MAXB + tid] = -1.f;
    }
  }
}

extern "C" void kernel_launch(void* const* d_in, const int* in_sizes, int n_in,
                              void* d_out, int out_size, void* d_ws, size_t ws_size,
                              hipStream_t stream) {
  (void)in_sizes; (void)n_in; (void)out_size; (void)ws_size;
  const float* p0 = (const float*)d_in[0];  // [16,20,20,255] anchors[6:9]
  const float* p1 = (const float*)d_in[1];  // [16,40,40,255] anchors[3:6]
  const float* p2 = (const float*)d_in[2];  // [16,80,80,255] anchors[0:3]
  char* ws = (char*)d_ws;
  float* boxes_ws = (float*)ws;              // 16*25200*16 B          -> 6,451,200
  int* cand_cnt = (int*)(ws + 6451200);      // 1280 i32               -> 6,456,320
  int* img_cnt = (int*)(ws + 6456320);       // 16 i32                 -> 6,456,384
  u64* cand_keys = (u64*)(ws + 6456384);     // 1280*4096 u64          -> 48,399,424
  u64* img_keys = (u64*)(ws + 48399424);     // 16*12000 u64           -> 49,935,424

  hipMemsetAsync(cand_cnt, 0, (NCLS * BATCH + BATCH) * sizeof(int), stream);

  // one wave per record: 403200 records = 25200 blocks of 16 waves
  decode_kernel<<<25200, 1024, 0, stream>>>(p0, p1, p2, boxes_ws,
                                            cand_keys, cand_cnt);
  nms_kernel<<<BATCH * NCLS, 256, 0, stream>>>(cand_keys, cand_cnt, boxes_ws,
                                               img_keys, img_cnt);
  final_kernel<<<BATCH, 1024, 0, stream>>>(img_keys, img_cnt, boxes_ws, (float*)d_out);
}